// Round 6
// baseline (659.528 us; speedup 1.0000x reference)
//
#include <hip/hip_runtime.h>

// ---------------------------------------------------------------------------
// TiedMultiheadAttention  (B=1, N=64, L=512, D=768, H=12, DK=64)
//
// R8: gemm256 v2 — race-free 1-deep staging (all staging into buf nxt;
//     boundary vmcnt(0)+lgkmcnt(0)). F32A path reg-stages fp32 A directly
//     (loads @p0, cvt+ds_write @p2/p3 into the proven bf16 XOR layout):
//     cvt_qk / cvt_bf16 / xb scratch deleted; Q/K/V fused into one z=3
//     launch. s2 split-K now writes 4 partial buffers into d_out (no
//     atomics, no memset); softmax sums the partials.
// ---------------------------------------------------------------------------

typedef __bf16 bf16x8 __attribute__((ext_vector_type(8)));
typedef float f32x4 __attribute__((ext_vector_type(4)));

__device__ __forceinline__ unsigned short f2bf(float f) {
  unsigned u = __float_as_uint(f);
  u += 0x7fffu + ((u >> 16) & 1u);  // RNE
  return (unsigned short)(u >> 16);
}

__device__ __forceinline__ void gll16(const void* g, void* l) {
  __builtin_amdgcn_global_load_lds(
      (const __attribute__((address_space(1))) unsigned int*)g,
      (__attribute__((address_space(3))) unsigned int*)l, 16, 0, 0);
}

#define BAR __builtin_amdgcn_s_barrier()

enum { MODE_PROJ = 0, MODE_ATT = 2, MODE_OUTWS = 3, MODE_OUT_BIAS = 4 };

// ========================= gemm256: 256x256x64, 8 waves =====================
// C = A @ B^T. B:[N,K] bf16 via global_load_lds (source-XOR-swizzled).
// F32A: A fp32, reg-staged (8x global_load_dwordx4 @p0 -> cvt -> ds_write
//       @p2/p3) into the same bf16 XOR LDS layout. !F32A: A bf16 via gll.
// All staging of tile T+1 goes into buf nxt (never the buffer being read).
// Boundary per tile: s_waitcnt vmcnt(0) lgkmcnt(0); s_barrier.
// MODE_PROJ: blockIdx.z = 0/1/2 -> Q/K/V (A ptr, bias, alpha, epilogue).
template <int MODE, bool F32A>
__global__ __launch_bounds__(512, 2) void gemm256(
    const void* __restrict__ A0, const void* __restrict__ A1,
    const void* __restrict__ A2, const unsigned short* __restrict__ Bw,
    const float* __restrict__ b0, const float* __restrict__ b1,
    const float* __restrict__ b2, void* __restrict__ Cv,
    int K, int lda, int ldb, long long b_bs,
    float alpha0, long long c_bs, int ntn) {
  __shared__ unsigned short L[2][2][16384];

  const int tid = threadIdx.x;
  const int wave = tid >> 6;
  const int lane = tid & 63;
  const int wm = wave >> 2;   // 0..1
  const int wn = wave & 3;    // 0..3
  const int l15 = lane & 15;
  const int kq8 = lane >> 4;  // 0..3
  const int sw = l15 & 7;

  const int bid = blockIdx.x;
  const int xcd = bid & 7;
  const int kk_ = bid >> 3;
  const int tn = kk_ % ntn;
  const int tm = (kk_ / ntn) * 8 + xcd;
  const int batch = blockIdx.z;

  const long long m0 = (long long)tm * 256;
  const long long n0 = (long long)tn * 256;

  const void* Abase;
  if constexpr (MODE == MODE_PROJ)
    Abase = batch == 0 ? A0 : (batch == 1 ? A1 : A2);
  else
    Abase = A0;
  const float* Af = (const float*)Abase;
  const unsigned short* Ab = (const unsigned short*)Abase;
  const unsigned short* Bb = Bw + (long long)batch * b_bs;

  const long long rowAw = m0 + wave * 8 + (lane >> 3);
  const long long rowBw = n0 + wave * 8 + (lane >> 3);
  const int csw = ((lane & 7) ^ (lane >> 3)) * 8;  // XOR-pre-swizzled col (elems)

  f32x4 acc[8][4] = {};
  f32x4 areg[4][2];

  // fp32 A: load 8 consecutive fp32 at the swizzled chunk (2 x dwordx4)
  auto loadA = [&](int k0) {
#pragma unroll
    for (int q = 0; q < 4; ++q) {
      const float* s = Af + (rowAw + (q << 6)) * (long long)lda + k0 + csw;
      areg[q][0] = *(const f32x4*)s;
      areg[q][1] = *(const f32x4*)(s + 4);
    }
  };
  // cvt + ds_write_b128: lane slot = lane*8 shorts -> slot (lane&7) of row
  // (wave*8 + lane>>3) holds logical chunk (lane&7)^(lane>>3) = slot^(row&7).
  auto writeA = [&](int buf, int q) {
    bf16x8 w;
    w[0] = (__bf16)areg[q][0][0]; w[1] = (__bf16)areg[q][0][1];
    w[2] = (__bf16)areg[q][0][2]; w[3] = (__bf16)areg[q][0][3];
    w[4] = (__bf16)areg[q][1][0]; w[5] = (__bf16)areg[q][1][1];
    w[6] = (__bf16)areg[q][1][2]; w[7] = (__bf16)areg[q][1][3];
    *(bf16x8*)&L[buf][0][(q << 12) + (wave << 9) + lane * 8] = w;
  };
  auto stA16 = [&](int buf, int q, int k0) {
    gll16(Ab + (rowAw + (q << 6)) * (long long)lda + k0 + csw,
          &L[buf][0][(q << 12) + (wave << 9)]);
  };
  auto stB = [&](int buf, int q, int k0) {
    gll16(Bb + (rowBw + (q << 6)) * (long long)ldb + k0 + csw,
          &L[buf][1][(q << 12) + (wave << 9)]);
  };

  // bias preload (no stray VMEM inside the K-loop)
  float bpre[4] = {};
  float aa = 1.0f;
  if constexpr (MODE == MODE_PROJ) {
    const float* bb = batch == 0 ? b0 : (batch == 1 ? b1 : b2);
    aa = batch == 0 ? alpha0 : 1.0f;
#pragma unroll
    for (int u = 0; u < 4; ++u) bpre[u] = bb[n0 + wn * 64 + u * 16 + l15];
  } else if constexpr (MODE == MODE_OUT_BIAS) {
#pragma unroll
    for (int u = 0; u < 4; ++u) bpre[u] = b0[n0 + wn * 64 + u * 16 + l15];
  }

  // Prologue: stage tile 0 into buf 0, drain, sync.
  if constexpr (F32A) {
    loadA(0);
#pragma unroll
    for (int q = 0; q < 4; ++q) stB(0, q, 0);
#pragma unroll
    for (int q = 0; q < 4; ++q) writeA(0, q);  // compiler waits areg loads
  } else {
#pragma unroll
    for (int q = 0; q < 4; ++q) stA16(0, q, 0);
#pragma unroll
    for (int q = 0; q < 4; ++q) stB(0, q, 0);
  }
  asm volatile("s_waitcnt vmcnt(0) lgkmcnt(0)" ::: "memory");
  BAR;

  const int NT = K >> 6;
  for (int T = 0; T < NT; ++T) {
    const int cur = T & 1, nxt = cur ^ 1;
    const int k1 = (T + 1) << 6;
    const bool more = (T + 1 < NT);
#pragma unroll
    for (int p = 0; p < 4; ++p) {
      const int kc = p >> 1, mh = p & 1;
      bf16x8 af[4], bfr[4];
#pragma unroll
      for (int mf = 0; mf < 4; ++mf) {
        const int row = wm * 128 + mh * 64 + mf * 16 + l15;
        af[mf] = *(const bf16x8*)&L[cur][0][row * 64 + (((kc << 2) + kq8) ^ sw) * 8];
      }
#pragma unroll
      for (int u = 0; u < 4; ++u) {
        const int row = wn * 64 + u * 16 + l15;
        bfr[u] = *(const bf16x8*)&L[cur][1][row * 64 + (((kc << 2) + kq8) ^ sw) * 8];
      }
      if (p == 0 && more) {
        if constexpr (F32A) {
          loadA(k1);
#pragma unroll
          for (int q = 0; q < 4; ++q) stB(nxt, q, k1);
        } else {
#pragma unroll
          for (int q = 0; q < 4; ++q) stA16(nxt, q, k1);
#pragma unroll
          for (int q = 0; q < 4; ++q) stB(nxt, q, k1);
        }
      }
      if constexpr (F32A) {
        if (p == 2 && more) { writeA(nxt, 0); writeA(nxt, 1); }
        if (p == 3 && more) { writeA(nxt, 2); writeA(nxt, 3); }
      }
      __builtin_amdgcn_s_setprio(1);
#pragma unroll
      for (int mf = 0; mf < 4; ++mf)
#pragma unroll
        for (int u = 0; u < 4; ++u)
          acc[mh * 4 + mf][u] = __builtin_amdgcn_mfma_f32_16x16x32_bf16(
              af[mf], bfr[u], acc[mh * 4 + mf][u], 0, 0, 0);
      __builtin_amdgcn_s_setprio(0);
      if (p < 3) {
        BAR;
      } else if (more) {
        asm volatile("s_waitcnt vmcnt(0) lgkmcnt(0)" ::: "memory");
        BAR;
      }
    }
  }

  // Epilogue
#pragma unroll
  for (int mf = 0; mf < 8; ++mf) {
#pragma unroll
    for (int u = 0; u < 4; ++u) {
      const long long col = n0 + wn * 64 + u * 16 + l15;
#pragma unroll
      for (int r = 0; r < 4; ++r) {
        const long long row = m0 + wm * 128 + mf * 16 + (lane >> 4) * 4 + r;
        float v = acc[mf][u][r];
        if constexpr (MODE == MODE_PROJ) {
          if (batch < 2) {  // Q/K -> [h][i][n][k] concat layout
            const float vv = (v + bpre[u]) * aa;
            const long long h = col >> 6, kq = col & 63, n = row >> 9, i = row & 511;
            ((unsigned short*)Cv + batch * c_bs)[((h * 512 + i) << 12) + (n << 6) + kq] =
                f2bf(vv);
          } else {          // V -> [h][n][k][j] transposed layout
            const float vv = v + bpre[u];
            const long long h = col >> 6, kq = col & 63, n = row >> 9, j = row & 511;
            ((unsigned short*)Cv + 2 * c_bs)[(((h << 12) + (n << 6) + kq) << 9) + j] =
                f2bf(vv);
          }
        } else {  // MODE_OUT_BIAS
          ((float*)Cv)[row * 768 + col] = v + bpre[u];
        }
      }
    }
  }
}

// ================== R5 128x128 kernel (s2 / s4) =============================
constexpr int BM = 128, BN = 128, BK = 32;

template <int MODE, bool SWZ, int KS>
__global__ __launch_bounds__(256, 2) void gemm_bt(
    const void* __restrict__ Av, const void* __restrict__ Bv,
    const float* __restrict__ bias, void* __restrict__ Cv,
    int K, int lda, int ldb, long long a_bs, long long b_bs,
    float alpha, int ntn, long long c_bs) {
  constexpr int LP = 32;

  __shared__ unsigned short As0[BM * LP];
  __shared__ unsigned short Bs0[BN * LP];
  __shared__ unsigned short As1[BM * LP];
  __shared__ unsigned short Bs1[BN * LP];

  const int tid = threadIdx.x;
  const int wave = tid >> 6;
  const int lane = tid & 63;
  const int wm = wave >> 1, wn = wave & 1;

  int tm, tn, batch = 0, ks = 0;
  if constexpr (SWZ && MODE == MODE_ATT) {
    const int bid = blockIdx.x;
    const int xcd = bid & 7, j = bid >> 3;
    const int z = (j >> 4) * 8 + xcd;   // 0..47, z%8 == xcd
    const int tile = j & 15;
    tn = tile & 3;
    tm = tile >> 2;
    ks = z % KS;
    batch = z / KS;
  } else if constexpr (SWZ && MODE == MODE_OUTWS) {
    const int bid = blockIdx.x;
    const int xcd = bid & 7, j = bid >> 3;
    const int g = (j >> 6) * 8 + xcd;   // 0..23, g%8 == xcd
    const int idx = j & 63;
    batch = g >> 1;                     // head
    tm = idx >> 4;
    tn = (g & 1) * 16 + (idx & 15);
  } else {
    tn = blockIdx.x;
    tm = blockIdx.y;
    batch = blockIdx.z;
    if constexpr (KS > 1) { ks = batch % KS; batch /= KS; }
  }

  const long long m0 = (long long)tm * BM;
  const long long n0 = (long long)tn * BN;

  const unsigned short* Ab = (const unsigned short*)Av + (long long)batch * a_bs + (long long)ks * K;
  const unsigned short* Bb = (const unsigned short*)Bv + (long long)batch * b_bs + (long long)ks * K;

  f32x4 acc[4][4] = {};

  const int l15 = lane & 15;
  const int kq = (lane >> 4) * 8;
  const int r_in = lane >> 2;
  const int c8 = (lane & 3) * 8;

  auto stage = [&](unsigned short* Asb, unsigned short* Bsb, int k0) {
#pragma unroll
    for (int t = 0; t < 2; ++t) {
      const int rb = t * 64 + wave * 16;
      gll16(Ab + (m0 + rb + r_in) * (long long)lda + k0 + c8, &Asb[rb * LP]);
      gll16(Bb + (n0 + rb + r_in) * (long long)ldb + k0 + c8, &Bsb[rb * LP]);
    }
  };
  auto compute = [&](const unsigned short* Asb, const unsigned short* Bsb) {
    bf16x8 af[4], bfr[4];
#pragma unroll
    for (int t = 0; t < 4; ++t)
      af[t] = *(const bf16x8*)&Asb[(wm * 64 + t * 16 + l15) * LP + kq];
#pragma unroll
    for (int u = 0; u < 4; ++u)
      bfr[u] = *(const bf16x8*)&Bsb[(wn * 64 + u * 16 + l15) * LP + kq];
#pragma unroll
    for (int t = 0; t < 4; ++t)
#pragma unroll
      for (int u = 0; u < 4; ++u)
        acc[t][u] = __builtin_amdgcn_mfma_f32_16x16x32_bf16(af[t], bfr[u], acc[t][u], 0, 0, 0);
  };

  stage(As0, Bs0, 0);
  asm volatile("s_waitcnt vmcnt(0)" ::: "memory");
  BAR;

  const int NT = K >> 5;
  for (int t = 0; t < NT; t += 2) {
    stage(As1, Bs1, (t + 1) << 5);
    asm volatile("s_waitcnt vmcnt(4)" ::: "memory");
    BAR;
    compute(As0, Bs0);
    BAR;
    if (t + 2 < NT) {
      stage(As0, Bs0, (t + 2) << 5);
      asm volatile("s_waitcnt vmcnt(4)" ::: "memory");
    } else {
      asm volatile("s_waitcnt vmcnt(0)" ::: "memory");
    }
    BAR;
    compute(As1, Bs1);
    BAR;
  }

#pragma unroll
  for (int t = 0; t < 4; ++t) {
#pragma unroll
    for (int u = 0; u < 4; ++u) {
      const long long col = n0 + wn * 64 + u * 16 + l15;
#pragma unroll
      for (int r = 0; r < 4; ++r) {
        const long long row = m0 + wm * 64 + t * 16 + (lane >> 4) * 4 + r;
        float v = acc[t][u][r];
        if constexpr (MODE == MODE_ATT) {
          // split-K partial buffers: [ks][h][i][j], plain coalesced stores
          ((float*)Cv)[((long long)(ks * 12 + batch) << 18) + (row << 9) + col] = v;
        } else if constexpr (MODE == MODE_OUTWS) {
          const long long n = col >> 6, kk = col & 63;
          ((unsigned short*)Cv)[(n * 512 + row) * 768 + (long long)batch * 64 + kk] = f2bf(v);
        } else {
          ((float*)Cv)[row * 768 + col] = v + alpha;  // unused modes
        }
      }
    }
  }
}

// softmax over last dim with 4-way split-K partial sum:
// att fp32 partials [4][12][512][512] -> bf16 [12][512][512]
__global__ __launch_bounds__(256) void softmax_rows(const float* __restrict__ att,
                                                    unsigned short* __restrict__ outb) {
  const long long rowbase = (long long)blockIdx.x << 9;
  const int tid = threadIdx.x;
  float a = 0.0f, b = 0.0f;
#pragma unroll
  for (int s = 0; s < 4; ++s) {
    a += att[(long long)s * 3145728 + rowbase + tid];
    b += att[(long long)s * 3145728 + rowbase + tid + 256];
  }

  float m = fmaxf(a, b);
#pragma unroll
  for (int off = 32; off; off >>= 1) m = fmaxf(m, __shfl_down(m, off));
  __shared__ float redm[4];
  if ((tid & 63) == 0) redm[tid >> 6] = m;
  __syncthreads();
  m = fmaxf(fmaxf(redm[0], redm[1]), fmaxf(redm[2], redm[3]));

  const float e0 = __expf(a - m), e1 = __expf(b - m);
  float s = e0 + e1;
#pragma unroll
  for (int off = 32; off; off >>= 1) s += __shfl_down(s, off);
  __shared__ float reds[4];
  if ((tid & 63) == 0) reds[tid >> 6] = s;
  __syncthreads();
  s = reds[0] + reds[1] + reds[2] + reds[3];

  const float inv = 1.0f / s;
  outb[rowbase + tid] = f2bf(e0 * inv);
  outb[rowbase + tid + 256] = f2bf(e1 * inv);
}

// fp32 -> bf16 for the four 768x768 weights in one launch
__global__ __launch_bounds__(256) void cvt_w4(
    const float* __restrict__ s0, const float* __restrict__ s1,
    const float* __restrict__ s2, const float* __restrict__ s3,
    unsigned short* __restrict__ d0, unsigned short* __restrict__ d1,
    unsigned short* __restrict__ d2, unsigned short* __restrict__ d3) {
  const float* s;
  unsigned short* d;
  switch (blockIdx.y) {
    case 0: s = s0; d = d0; break;
    case 1: s = s1; d = d1; break;
    case 2: s = s2; d = d2; break;
    default: s = s3; d = d3; break;
  }
  const long long i = ((long long)blockIdx.x * 256 + threadIdx.x) * 8;
  const float4 a = *(const float4*)(s + i);
  const float4 b = *(const float4*)(s + i + 4);
  uint4 p;
  p.x = (unsigned)f2bf(a.x) | ((unsigned)f2bf(a.y) << 16);
  p.y = (unsigned)f2bf(a.z) | ((unsigned)f2bf(a.w) << 16);
  p.z = (unsigned)f2bf(b.x) | ((unsigned)f2bf(b.y) << 16);
  p.w = (unsigned)f2bf(b.z) | ((unsigned)f2bf(b.w) << 16);
  *(uint4*)(d + i) = p;
}

extern "C" void kernel_launch(void* const* d_in, const int* in_sizes, int n_in,
                              void* d_out, int out_size, void* d_ws, size_t ws_size,
                              hipStream_t stream) {
  const float* query = (const float*)d_in[0];
  const float* key   = (const float*)d_in[1];
  const float* value = (const float*)d_in[2];
  const float* Wq = (const float*)d_in[3];
  const float* bq = (const float*)d_in[4];
  const float* Wk = (const float*)d_in[5];
  const float* bk = (const float*)d_in[6];
  const float* Wv = (const float*)d_in[7];
  const float* bv = (const float*)d_in[8];
  const float* Wo = (const float*)d_in[9];
  const float* bo = (const float*)d_in[10];
  float* out = (float*)d_out;

  char* ws = (char*)d_ws;
  unsigned short* q_ws  = (unsigned short*)(ws);               // 50,331,648 B
  unsigned short* k_ws  = (unsigned short*)(ws + 50331648);    // 50,331,648 B
  unsigned short* vt_ws = (unsigned short*)(ws + 100663296);   // 50,331,648 B
  // bf16 weights, contiguous (b_bs = 589824 shorts strides wq->wk->wv)
  unsigned short* wq_b  = (unsigned short*)(ws + 150994944);
  unsigned short* wk_b  = (unsigned short*)(ws + 150994944 + 1179648);
  unsigned short* wv_b  = (unsigned short*)(ws + 150994944 + 2359296);
  unsigned short* wo_b  = (unsigned short*)(ws + 150994944 + 3538944);
  unsigned short* att_b = k_ws;   // k_ws dead after s2
  unsigned short* out_ws = q_ws;  // q_ws dead after s2
  // split-K score partials live in d_out (dead until s5): 4 x 12.58 MB
  float* att_part = (float*)d_out;

  const dim3 blk(256);
  const dim3 blk5(512);

  // s0: weights fp32 -> bf16
  cvt_w4<<<dim3(288, 4), blk, 0, stream>>>(Wq, Wk, Wv, Wo, wq_b, wk_b, wv_b, wo_b);

  // s1: Q/K/V projections fused (z=3), fp32 A reg-staged in-kernel.
  //     Outputs q_ws/k_ws/vt_ws contiguous (c_bs = 25165824 shorts).
  gemm256<MODE_PROJ, true><<<dim3(384, 1, 3), blk5, 0, stream>>>(
      query, key, value, wq_b, bq, bk, bv, q_ws,
      768, 768, 768, 589824LL, 0.015625f, 25165824LL, 3);

  // s2: tied scores, per-head [512 x 4096] @ [512 x 4096]^T, split-K x4
  //     -> 4 partial buffers in d_out (no atomics, no memset).
  gemm_bt<MODE_ATT, true, 4><<<dim3(768, 1, 1), blk, 0, stream>>>(
      q_ws, k_ws, nullptr, att_part, 1024, 4096, 4096, 2097152LL, 2097152LL,
      1.0f, 0, 0);

  // s3: softmax (sums the 4 partials)
  softmax_rows<<<6144, blk, 0, stream>>>(att_part, att_b);

  // s4: per-head att @ Vt^T -> out_ws [(n*512+i)][h*64+k]
  gemm_bt<MODE_OUTWS, true, 1><<<dim3(1536, 1, 1), blk, 0, stream>>>(
      att_b, vt_ws, nullptr, out_ws, 512, 512, 512, 262144LL, 2097152LL,
      1.0f, 0, 0);

  // s5: output projection -> fp32 d_out (overwrites the partials)
  gemm256<MODE_OUT_BIAS, false><<<dim3(384, 1, 1), blk5, 0, stream>>>(
      out_ws, nullptr, nullptr, wo_b, bo, nullptr, nullptr, out,
      768, 768, 768, 0, 1.0f, 0, 3);
}